// Round 2
// baseline (291.767 us; speedup 1.0000x reference)
//
#include <hip/hip_runtime.h>

// KPN per-pixel dynamic kernel conv.
// data:    [1, 8, 3, 96, 96]          fp32   (~0.9 MB, L1/L2-resident)
// kernels: [1, 8, 225, 3, 96, 96]     fp32   (199 MB -> the streaming read)
// out:     [1, 8, 3, 96, 96]          fp32
// out[t,c,h,w] = sum_{i,j} kernels[t, i*15+j, c, h, w] * data[t,c,h+i-7,w+j-7] (zero pad)
//
// Design: barrier-free, LDS-free (deterministic across graph replays).
// One thread = one float4 output quad, all 225 taps. 864 blocks x 64 threads
// -> every CU gets 3-4 waves; each j-loop issues 15 outstanding dwordx4
// wave-loads (1 KiB each, perfectly coalesced) before consuming them.

constexpr int K   = 15;
constexpr int P   = 7;
constexpr int H   = 96;
constexpr int W   = 96;
constexpr int C   = 3;
constexpr int T   = 8;
constexpr int HW  = H * W;        // 9216
constexpr int K2  = K * K;        // 225
constexpr int QW  = W / 4;        // 24 quads per row
constexpr int QPP = H * QW;       // 2304 quads per plane
constexpr int NQ  = T * C * QPP;  // 55296 quads total
constexpr int BLK = 64;           // one wave per block
constexpr int NBLK = NQ / BLK;    // 864 blocks

__global__ __launch_bounds__(BLK) void kpn_kernel(
    const float* __restrict__ data,
    const float* __restrict__ kern,
    float* __restrict__ out)
{
    const int q = blockIdx.x * BLK + threadIdx.x;

    const int w4    = q % QW;
    const int rem   = q / QW;
    const int h     = rem % H;
    const int plane = rem / H;           // t*C + c
    const int t     = plane / C;
    const int c     = plane % C;
    const int wbase = w4 * 4;

    const float* __restrict__ dplane = data + plane * HW;
    // kernels offset for tap k: ((t*K2 + k)*C + c)*HW + h*W + wbase
    const float* __restrict__ kbase =
        kern + ((size_t)(t * K2) * C + (size_t)c) * HW + (size_t)h * W + wbase;
    const size_t kstride = (size_t)C * HW;   // per-tap stride in floats (27648)

    // Column clamp/validity is row-independent: precompute once.
    int  colc[K + 3];
    bool cval[K + 3];
    #pragma unroll
    for (int m = 0; m < K + 3; ++m) {
        const int col = wbase - P + m;
        cval[m] = (col >= 0) && (col < W);
        colc[m] = (col < 0) ? 0 : ((col >= W) ? (W - 1) : col);
    }

    float4 acc = make_float4(0.f, 0.f, 0.f, 0.f);

    for (int i = 0; i < K; ++i) {
        const int srow = h + i - P;
        const bool rv  = (srow >= 0) && (srow < H);
        const float* __restrict__ drow = dplane + (rv ? srow : 0) * W;

        // 18-wide data window covering cols [wbase-7, wbase+10] (L1/L2 hits)
        float dwin[K + 3];
        #pragma unroll
        for (int m = 0; m < K + 3; ++m) {
            const float v = drow[colc[m]];            // always in-bounds address
            dwin[m] = (rv && cval[m]) ? v : 0.f;
        }

        const float* __restrict__ krow = kbase + (size_t)(i * K) * kstride;

        // Issue all 15 streaming loads first (15 outstanding dwordx4 / wave),
        // then consume.
        float4 kv[K];
        #pragma unroll
        for (int j = 0; j < K; ++j) {
            kv[j] = *reinterpret_cast<const float4*>(krow + (size_t)j * kstride);
        }
        #pragma unroll
        for (int j = 0; j < K; ++j) {
            acc.x += kv[j].x * dwin[j + 0];
            acc.y += kv[j].y * dwin[j + 1];
            acc.z += kv[j].z * dwin[j + 2];
            acc.w += kv[j].w * dwin[j + 3];
        }
    }

    *reinterpret_cast<float4*>(out + (size_t)plane * HW + (size_t)h * W + wbase) = acc;
}

extern "C" void kernel_launch(void* const* d_in, const int* in_sizes, int n_in,
                              void* d_out, int out_size, void* d_ws, size_t ws_size,
                              hipStream_t stream) {
    const float* data = (const float*)d_in[0];
    const float* kern = (const float*)d_in[1];
    float* out        = (float*)d_out;
    hipLaunchKernelGGL(kpn_kernel, dim3(NBLK), dim3(BLK), 0, stream,
                       data, kern, out);
}

// Round 3
// 288.534 us; speedup vs baseline: 1.0112x; 1.0112x over previous
//
#include <hip/hip_runtime.h>

// KPN per-pixel dynamic kernel conv.
// data:    [1, 8, 3, 96, 96]        fp32 (~0.9 MB, cache-resident)
// kernels: [1, 8, 225, 3, 96, 96]   fp32 (199 MB streaming read)
// out:     [1, 8, 3, 96, 96]        fp32
// out[t,c,h,w] = sum_{i,j} kernels[t,i*15+j,c,h,w] * data[t,c,h+i-7,w+j-7] (zero pad)
//
// Round 3: (a) 3 KiB contiguous per wave per tap (12 px/thread), (b) tap-row
// split x15 with per-row partials in d_ws + deterministic reduce kernel.
// 4320 waves (~17/CU). No LDS / barriers / atomics anywhere.

constexpr int K    = 15;
constexpr int P    = 7;
constexpr int H    = 96;
constexpr int W    = 96;
constexpr int C    = 3;
constexpr int T    = 8;
constexpr int HW   = H * W;           // 9216
constexpr int K2   = K * K;           // 225
constexpr int NP   = T * C;           // 24 planes
constexpr int NE   = NP * HW;         // 221184 output elems
constexpr int PXT  = 12;              // pixels per thread (3 float4)
constexpr int ROWS_PER_WAVE = 8;      // 64 lanes = 8 rows x 8 col-groups
constexpr int TILES = NP * (H / ROWS_PER_WAVE);  // 288 wave-tiles
constexpr int NWAVE1 = TILES * K;     // 4320 waves (one tap-row each)
constexpr int BLK1 = 256;
constexpr int NBLK1 = NWAVE1 / 4;     // 1080 blocks
constexpr size_t PART_FLOATS = (size_t)K * NE;          // 3,317,760 floats
constexpr size_t PART_BYTES  = PART_FLOATS * 4;         // 13.3 MB

__device__ __forceinline__ void tap_row_accum(
    const float* __restrict__ data, const float* __restrict__ kern,
    int plane, int t, int c, int r, int cg, int i,
    float4& a0, float4& a1, float4& a2)
{
    const int srow = r + i - P;
    const bool rv  = (srow >= 0) && (srow < H);
    const float* __restrict__ drow = data + plane * HW + (rv ? srow : 0) * W;

    // 26-wide window: data cols [cg-7, cg+18], clamped addresses, zeroed pad.
    float dwin[26];
    #pragma unroll
    for (int m = 0; m < 26; ++m) {
        const int col = cg - P + m;
        const int cc  = (col < 0) ? 0 : ((col >= W) ? (W - 1) : col);
        const float v = drow[cc];
        dwin[m] = (rv && col >= 0 && col < W) ? v : 0.f;
    }

    const float* __restrict__ kptr =
        kern + ((size_t)((t * K2 + i * K) * C + c)) * HW + (size_t)r * W + cg;

    #pragma unroll
    for (int j = 0; j < K; ++j) {
        const float4* __restrict__ kp =
            reinterpret_cast<const float4*>(kptr + (size_t)j * (C * HW));
        const float4 k0 = kp[0];
        const float4 k1 = kp[1];
        const float4 k2 = kp[2];
        a0.x += k0.x * dwin[j + 0];  a0.y += k0.y * dwin[j + 1];
        a0.z += k0.z * dwin[j + 2];  a0.w += k0.w * dwin[j + 3];
        a1.x += k1.x * dwin[j + 4];  a1.y += k1.y * dwin[j + 5];
        a1.z += k1.z * dwin[j + 6];  a1.w += k1.w * dwin[j + 7];
        a2.x += k2.x * dwin[j + 8];  a2.y += k2.y * dwin[j + 9];
        a2.z += k2.z * dwin[j + 10]; a2.w += k2.w * dwin[j + 11];
    }
}

__global__ __launch_bounds__(BLK1, 4) void kpn_part(
    const float* __restrict__ data,
    const float* __restrict__ kern,
    float* __restrict__ part)
{
    const int w    = blockIdx.x * 4 + (threadIdx.x >> 6);  // wave id 0..4319
    const int lane = threadIdx.x & 63;
    const int i    = w / TILES;          // tap row 0..14
    const int tile = w % TILES;          // consecutive waves -> same i, adjacent tiles
    const int plane = tile / (H / ROWS_PER_WAVE);
    const int rb    = tile % (H / ROWS_PER_WAVE);
    const int t = plane / C;
    const int c = plane % C;
    const int r  = rb * ROWS_PER_WAVE + (lane >> 3);  // output row
    const int cg = (lane & 7) * PXT;                  // first col (mult of 12)

    float4 a0 = make_float4(0.f,0.f,0.f,0.f);
    float4 a1 = a0, a2 = a0;
    tap_row_accum(data, kern, plane, t, c, r, cg, i, a0, a1, a2);

    float* pp = part + (size_t)i * NE + (size_t)plane * HW + (size_t)r * W + cg;
    reinterpret_cast<float4*>(pp)[0] = a0;
    reinterpret_cast<float4*>(pp)[1] = a1;
    reinterpret_cast<float4*>(pp)[2] = a2;
}

__global__ __launch_bounds__(256) void kpn_reduce(
    const float4* __restrict__ part, float4* __restrict__ out)
{
    const int e = blockIdx.x * 256 + threadIdx.x;   // 0..55295 (NE/4)
    float4 s = make_float4(0.f,0.f,0.f,0.f);
    #pragma unroll
    for (int i = 0; i < K; ++i) {
        const float4 p = part[(size_t)i * (NE / 4) + e];
        s.x += p.x; s.y += p.y; s.z += p.z; s.w += p.w;
    }
    out[e] = s;
}

// Fallback if d_ws is too small: fused single kernel, same mapping, all 15 rows.
__global__ __launch_bounds__(BLK1) void kpn_fused(
    const float* __restrict__ data,
    const float* __restrict__ kern,
    float* __restrict__ out)
{
    const int w    = blockIdx.x * 4 + (threadIdx.x >> 6);  // tile 0..287
    const int lane = threadIdx.x & 63;
    const int plane = w / (H / ROWS_PER_WAVE);
    const int rb    = w % (H / ROWS_PER_WAVE);
    const int t = plane / C;
    const int c = plane % C;
    const int r  = rb * ROWS_PER_WAVE + (lane >> 3);
    const int cg = (lane & 7) * PXT;

    float4 a0 = make_float4(0.f,0.f,0.f,0.f);
    float4 a1 = a0, a2 = a0;
    for (int i = 0; i < K; ++i)
        tap_row_accum(data, kern, plane, t, c, r, cg, i, a0, a1, a2);

    float* op = out + (size_t)plane * HW + (size_t)r * W + cg;
    reinterpret_cast<float4*>(op)[0] = a0;
    reinterpret_cast<float4*>(op)[1] = a1;
    reinterpret_cast<float4*>(op)[2] = a2;
}

extern "C" void kernel_launch(void* const* d_in, const int* in_sizes, int n_in,
                              void* d_out, int out_size, void* d_ws, size_t ws_size,
                              hipStream_t stream) {
    const float* data = (const float*)d_in[0];
    const float* kern = (const float*)d_in[1];
    float* out        = (float*)d_out;

    if (ws_size >= PART_BYTES) {
        float* part = (float*)d_ws;
        hipLaunchKernelGGL(kpn_part, dim3(NBLK1), dim3(BLK1), 0, stream,
                           data, kern, part);
        hipLaunchKernelGGL(kpn_reduce, dim3(NE / 4 / 256), dim3(256), 0, stream,
                           (const float4*)part, (float4*)out);
    } else {
        hipLaunchKernelGGL(kpn_fused, dim3(TILES / 4), dim3(BLK1), 0, stream,
                           data, kern, out);
    }
}

// Round 4
// 277.193 us; speedup vs baseline: 1.0526x; 1.0409x over previous
//
#include <hip/hip_runtime.h>

// KPN per-pixel dynamic kernel conv.
// data:    [1, 8, 3, 96, 96]        fp32 (~0.9 MB, cache-resident)
// kernels: [1, 8, 225, 3, 96, 96]   fp32 (199 MB streaming read)
// out:     [1, 8, 3, 96, 96]        fp32
// out[t,c,h,w] = sum_{i,j} kernels[t,i*15+j,c,h,w] * data[t,c,h+i-7,w+j-7] (zero pad)
//
// Round 4: attack latency-bound profile (VALUBusy 0.6%, occ 4.2%, 653 GB/s).
//  - 12960 waves (tap-row i split x15, tile = 8 rows x 32 cols, 1 quad/thread)
//  - all 15 streaming dwordx4 batched in VGPRs before first use
//  - __launch_bounds__(256,4): <=128 VGPR -> 16 waves/CU resident
// No LDS / barriers / atomics -> deterministic across graph replays.

constexpr int K   = 15;
constexpr int P   = 7;
constexpr int H   = 96;
constexpr int W   = 96;
constexpr int C   = 3;
constexpr int T   = 8;
constexpr int HW  = H * W;            // 9216
constexpr int K2  = K * K;            // 225
constexpr int NP  = T * C;            // 24 planes
constexpr int NE  = NP * HW;          // 221184 output elems
constexpr int TR  = 8;                // tile rows per wave
constexpr int TC  = 32;               // tile cols per wave (8 quads)
constexpr int TPP = (H / TR) * (W / TC);   // 36 tiles per plane
constexpr int TILES = NP * TPP;       // 864 tiles
constexpr int NWAVES = TILES * K;     // 12960 waves
constexpr int NBLK1  = NWAVES / 4;    // 3240 blocks of 256
constexpr size_t PART_BYTES = (size_t)K * NE * 4;   // 13.3 MB

__global__ __launch_bounds__(256, 4) void kpn_part(
    const float* __restrict__ data,
    const float* __restrict__ kern,
    float* __restrict__ part)
{
    const int w    = blockIdx.x * 4 + (threadIdx.x >> 6);  // wave 0..12959
    const int lane = threadIdx.x & 63;
    const int i    = w / TILES;        // tap row (864 % 4 == 0: block-uniform)
    const int tile = w % TILES;        // adjacent waves -> adjacent tiles, same i
    const int plane = tile / TPP;      // t*C + c
    const int tp    = tile % TPP;
    const int rg    = tp / (W / TC);   // 0..11
    const int cgp   = tp % (W / TC);   // 0..2
    const int r     = rg * TR + (lane >> 3);        // output row
    const int col   = cgp * TC + (lane & 7) * 4;    // first output col
    const int t = plane / C;
    const int c = plane % C;

    // --- issue all 15 streaming loads first (keep them in flight) ---
    const float* __restrict__ kptr =
        kern + ((size_t)((t * K2 + i * K) * C + c)) * HW + (size_t)r * W + col;
    float4 kv[K];
    #pragma unroll
    for (int j = 0; j < K; ++j) {
        kv[j] = *reinterpret_cast<const float4*>(kptr + (size_t)j * (C * HW));
    }

    // --- build 18-wide data window (L1/L2-hit) while loads are in flight ---
    const int srow = r + i - P;
    const bool rv  = (srow >= 0) && (srow < H);
    const float* __restrict__ drow = data + plane * HW + (rv ? srow : 0) * W;
    float dwin[K + 3];
    #pragma unroll
    for (int m = 0; m < K + 3; ++m) {
        const int cc  = col - P + m;
        const int ccc = (cc < 0) ? 0 : ((cc >= W) ? (W - 1) : cc);
        const float v = drow[ccc];                  // address always in-bounds
        dwin[m] = (rv && cc >= 0 && cc < W) ? v : 0.f;
    }

    float4 acc = make_float4(0.f, 0.f, 0.f, 0.f);
    #pragma unroll
    for (int j = 0; j < K; ++j) {
        acc.x += kv[j].x * dwin[j + 0];
        acc.y += kv[j].y * dwin[j + 1];
        acc.z += kv[j].z * dwin[j + 2];
        acc.w += kv[j].w * dwin[j + 3];
    }

    float* pp = part + (size_t)i * NE + (size_t)plane * HW + (size_t)r * W + col;
    *reinterpret_cast<float4*>(pp) = acc;
}

__global__ __launch_bounds__(256) void kpn_reduce(
    const float4* __restrict__ part, float4* __restrict__ out)
{
    const int e = blockIdx.x * 256 + threadIdx.x;   // 0..55295 (NE/4)
    float4 p[K];
    #pragma unroll
    for (int i = 0; i < K; ++i) p[i] = part[(size_t)i * (NE / 4) + e];
    float4 s = make_float4(0.f, 0.f, 0.f, 0.f);
    #pragma unroll
    for (int i = 0; i < K; ++i) {
        s.x += p[i].x; s.y += p[i].y; s.z += p[i].z; s.w += p[i].w;
    }
    out[e] = s;
}

// Fallback if d_ws too small: fused, each thread all 225 taps (slow but correct).
__global__ __launch_bounds__(256, 4) void kpn_fused(
    const float* __restrict__ data,
    const float* __restrict__ kern,
    float* __restrict__ out)
{
    const int w    = blockIdx.x * 4 + (threadIdx.x >> 6);  // tile 0..863
    const int lane = threadIdx.x & 63;
    const int plane = w / TPP;
    const int tp    = w % TPP;
    const int rg    = tp / (W / TC);
    const int cgp   = tp % (W / TC);
    const int r     = rg * TR + (lane >> 3);
    const int col   = cgp * TC + (lane & 7) * 4;
    const int t = plane / C;
    const int c = plane % C;

    float4 acc = make_float4(0.f, 0.f, 0.f, 0.f);
    for (int i = 0; i < K; ++i) {
        const float* __restrict__ kptr =
            kern + ((size_t)((t * K2 + i * K) * C + c)) * HW + (size_t)r * W + col;
        float4 kv[K];
        #pragma unroll
        for (int j = 0; j < K; ++j)
            kv[j] = *reinterpret_cast<const float4*>(kptr + (size_t)j * (C * HW));

        const int srow = r + i - P;
        const bool rv  = (srow >= 0) && (srow < H);
        const float* __restrict__ drow = data + plane * HW + (rv ? srow : 0) * W;
        float dwin[K + 3];
        #pragma unroll
        for (int m = 0; m < K + 3; ++m) {
            const int cc  = col - P + m;
            const int ccc = (cc < 0) ? 0 : ((cc >= W) ? (W - 1) : cc);
            const float v = drow[ccc];
            dwin[m] = (rv && cc >= 0 && cc < W) ? v : 0.f;
        }
        #pragma unroll
        for (int j = 0; j < K; ++j) {
            acc.x += kv[j].x * dwin[j + 0];
            acc.y += kv[j].y * dwin[j + 1];
            acc.z += kv[j].z * dwin[j + 2];
            acc.w += kv[j].w * dwin[j + 3];
        }
    }
    float* op = out + (size_t)plane * HW + (size_t)r * W + col;
    *reinterpret_cast<float4*>(op) = acc;
}

extern "C" void kernel_launch(void* const* d_in, const int* in_sizes, int n_in,
                              void* d_out, int out_size, void* d_ws, size_t ws_size,
                              hipStream_t stream) {
    const float* data = (const float*)d_in[0];
    const float* kern = (const float*)d_in[1];
    float* out        = (float*)d_out;

    if (ws_size >= PART_BYTES) {
        float* part = (float*)d_ws;
        hipLaunchKernelGGL(kpn_part, dim3(NBLK1), dim3(256), 0, stream,
                           data, kern, part);
        hipLaunchKernelGGL(kpn_reduce, dim3(NE / 4 / 256), dim3(256), 0, stream,
                           (const float4*)part, (float4*)out);
    } else {
        hipLaunchKernelGGL(kpn_fused, dim3(TILES / 4), dim3(256), 0, stream,
                           data, kern, out);
    }
}